// Round 4
// baseline (45.677 us; speedup 1.0000x reference)
//
#include <hip/hip_runtime.h>
#include <math.h>

#define N_T   16384
#define CHUNK 4096
#define SEG   16            // elements per thread in K2 (256 thr * 16 = 4096)
#define CPR   4             // chunks per row

// XOR-swizzle word index: mix bits [6:8] into bits [2:4].
// Preserves 16B (float4) granularity; bijective within [0, 4096).
__device__ __forceinline__ int SW(int i) {
    return i ^ (((i >> 6) & 7) << 2);
}

// ---------------- K1: per-chunk jump-sum -> ws[chunk] ----------------
__global__ __launch_bounds__(256)
void chunk_sum_kernel(const float* __restrict__ x, int* __restrict__ ws) {
    const int c    = blockIdx.x;
    const int row  = c >> 2;
    const int cpos = c & 3;
    const int b    = row >> 6;
    const int ch   = row & 63;
    const float* __restrict__ pr =
        x + ((size_t)(b * 128 + 64 + ch)) * N_T + cpos * CHUNK;
    const int lane = threadIdx.x & 63;
    const int wv   = threadIdx.x >> 6;           // wave owns 1024 contiguous elems
    const float* __restrict__ wb = pr + wv * 1024;

    float carry = 0.0f;
    if (lane == 0 && !(cpos == 0 && wv == 0)) carry = wb[-1];
    carry = __shfl(carry, 0);

    int lsum = 0;
    #pragma unroll
    for (int i = 0; i < 4; ++i) {
        float4 v = *reinterpret_cast<const float4*>(wb + i * 256 + lane * 4);
        float up   = __shfl_up(v.w, 1);
        float prev = (lane == 0) ? carry : up;
        float g0 = v.x - prev;
        float g1 = v.y - v.x;
        float g2 = v.z - v.y;
        float g3 = v.w - v.z;
        bool first = (cpos == 0 && wv == 0 && i == 0 && lane == 0); // row elem 0
        if (!first && fabsf(g0) > 0.5f) lsum += (g0 > 0.0f) ? 1 : -1;
        if (fabsf(g1) > 0.5f)           lsum += (g1 > 0.0f) ? 1 : -1;
        if (fabsf(g2) > 0.5f)           lsum += (g2 > 0.0f) ? 1 : -1;
        if (fabsf(g3) > 0.5f)           lsum += (g3 > 0.0f) ? 1 : -1;
        carry = __shfl(v.w, 63);
    }
    #pragma unroll
    for (int off = 32; off; off >>= 1) lsum += __shfl_xor(lsum, off);

    __shared__ int ws4[4];
    if (lane == 0) ws4[wv] = lsum;
    __syncthreads();
    if (threadIdx.x == 0) ws[c] = ws4[0] + ws4[1] + ws4[2] + ws4[3];
}

// ---------------- K2: per-chunk scan + output ----------------
// MODE 0: real part only, flat; MODE 1: interleaved re/im.
template <int MODE>
__global__ __launch_bounds__(256)
void phase_kernel(const float* __restrict__ x, float* __restrict__ out,
                  const int* __restrict__ ws) {
    __shared__ float ph[CHUNK];   // 16 KB
    __shared__ int   wsum[4];

    const int tid  = threadIdx.x;
    const int lane = tid & 63;
    const int wv   = tid >> 6;
    const int c    = blockIdx.x;
    const int row  = c >> 2;
    const int cpos = c & 3;
    const int b    = row >> 6;
    const int ch   = row & 63;
    const float* __restrict__ phase_row =
        x + ((size_t)(b * 128 + 64 + ch)) * N_T + cpos * CHUNK;
    const float* __restrict__ mag_row =
        x + ((size_t)(b * 128 + ch)) * N_T + cpos * CHUNK;

    const float TWO_PI = 6.28318530717958647692f;
    const float PI_F   = 3.14159265358979323846f;
    const float THIRD  = 1.0f / 3.0f;

    // ---- 1. stage chunk phase into LDS (swizzled), coalesced float4 loads
    #pragma unroll
    for (int i = 0; i < 4; ++i) {
        int idx = (i * 256 + tid) * 4;
        float4 v = *reinterpret_cast<const float4*>(phase_row + idx);
        *reinterpret_cast<float4*>(&ph[SW(idx)]) = v;
    }
    __syncthreads();

    // ---- 2. own contiguous segment into registers; local d-sum
    const int seg0 = tid * SEG;
    float s[SEG];
    #pragma unroll
    for (int q = 0; q < SEG / 4; ++q) {
        float4 v = *reinterpret_cast<const float4*>(&ph[SW(seg0 + q * 4)]);
        s[q * 4 + 0] = v.x; s[q * 4 + 1] = v.y;
        s[q * 4 + 2] = v.z; s[q * 4 + 3] = v.w;
    }
    float prevseg = __shfl_up(s[SEG - 1], 1);
    if (lane == 0) {
        if (tid > 0)            prevseg = ph[SW(seg0 - 1)];
        else if (cpos > 0)      prevseg = phase_row[-1];
        else                    prevseg = 0.0f;   // unused (row elem 0 has d=0)
    }

    int lsum = 0;
    {
        float prev = prevseg;
        #pragma unroll
        for (int j = 0; j < SEG; ++j) {
            float g = s[j] - prev;
            bool first = (cpos == 0 && (seg0 + j) == 0);
            if (!first && fabsf(g) > 0.5f) lsum += (g > 0.0f) ? 1 : -1;
            prev = s[j];
        }
    }

    // ---- 3. wave scan + cross-wave + cross-chunk prefix
    int incl = lsum;
    #pragma unroll
    for (int off = 1; off < 64; off <<= 1) {
        int n = __shfl_up(incl, off);
        if (lane >= off) incl += n;
    }
    if (lane == 63) wsum[wv] = incl;
    __syncthreads();
    int wpre = 0;
    #pragma unroll
    for (int w = 0; w < 4; ++w) {
        int wt = wsum[w];
        if (w < wv) wpre += wt;
    }
    int P_c = 0;
    for (int k = 0; k < cpos; ++k) P_c += ws[row * CPR + k];  // uniform scalar loads

    int running = P_c + wpre + (incl - lsum);    // corr at seg0 (exclusive)

    // ---- 4. corrected phase in registers, write back (float4, swizzled)
    {
        float prev = prevseg;
        #pragma unroll
        for (int j = 0; j < SEG; ++j) {
            float cur = s[j];
            int d = 0;
            bool first = (cpos == 0 && (seg0 + j) == 0);
            if (!first) {
                float g = cur - prev;
                if (fabsf(g) > 0.5f) d = (g > 0.0f) ? 1 : -1;
            }
            s[j] = (cur - (float)running) * TWO_PI - PI_F;
            running += d;
            prev = cur;
        }
    }
    #pragma unroll
    for (int q = 0; q < SEG / 4; ++q) {
        *reinterpret_cast<float4*>(&ph[SW(seg0 + q * 4)]) =
            make_float4(s[q * 4 + 0], s[q * 4 + 1], s[q * 4 + 2], s[q * 4 + 3]);
    }

    // ---- chunk-edge neighbor values (exact recompute from raw x + int corr)
    float v_left = 0.0f, v_right = 0.0f;
    if (tid == 0 && cpos > 0) {
        float xm1 = phase_row[-1];
        float xm2 = phase_row[-2];
        float g = xm1 - xm2;
        int d = (fabsf(g) > 0.5f) ? ((g > 0.0f) ? 1 : -1) : 0;
        int corr = P_c - d;                       // corr[cL-1] = P_c - d[cL-1]
        v_left = (xm1 - (float)corr) * TWO_PI - PI_F;
    }
    if (tid == 255 && cpos < CPR - 1) {
        float xp = phase_row[CHUNK];
        int corr = P_c + ws[row * CPR + cpos];    // corr[(c+1)L] = P_c + S_c
        v_right = (xp - (float)corr) * TWO_PI - PI_F;
    }
    __syncthreads();

    // ---- 5. coalesced output pass
    #pragma unroll
    for (int i = 0; i < 4; ++i) {
        int e = (i * 256 + tid) * 4;
        float4 mg = *reinterpret_cast<const float4*>(mag_row + e);
        float4 pc = *reinterpret_cast<const float4*>(&ph[SW(e)]);

        float p_m1 = __shfl_up(pc.w, 1);
        if (lane == 0)  p_m1 = (e > 0) ? ph[SW(e - 1)] : v_left;
        float p_p4 = __shfl_down(pc.x, 1);
        if (lane == 63) p_p4 = (e + 4 < CHUNK) ? ph[SW(e + 4)] : v_right;

        float pv[6] = {p_m1, pc.x, pc.y, pc.z, pc.w, p_p4};
        float mgk[4] = {mg.x, mg.y, mg.z, mg.w};

        float re[4], im[4];
        #pragma unroll
        for (int k = 0; k < 4; ++k) {
            float sm = ((pv[k] + pv[k + 1]) + pv[k + 2]) * THIRD;
            float pf = 0.7f * pv[k + 1] + 0.3f * sm;
            // two-term range reduction: 2pi = hi + lo
            float nrev = rintf(pf * 0.15915494309189535f);
            float rr = fmaf(nrev, -6.28318548202514648f, pf);
            rr = fmaf(nrev, 1.74845553e-7f, rr);
            re[k] = mgk[k] * __cosf(rr);
            if (MODE == 1) im[k] = mgk[k] * __sinf(rr);
        }
        if (MODE == 0) {
            float* orow = out + (size_t)row * N_T + cpos * CHUNK;
            *reinterpret_cast<float4*>(orow + e) = make_float4(re[0], re[1], re[2], re[3]);
        } else {
            float* orow = out + (size_t)row * (2 * N_T) + cpos * (2 * CHUNK);
            *reinterpret_cast<float4*>(orow + 2 * e) =
                make_float4(re[0], im[0], re[1], im[1]);
            *reinterpret_cast<float4*>(orow + 2 * e + 4) =
                make_float4(re[2], im[2], re[3], im[3]);
        }
    }
}

extern "C" void kernel_launch(void* const* d_in, const int* in_sizes, int n_in,
                              void* d_out, int out_size, void* d_ws, size_t ws_size,
                              hipStream_t stream) {
    const float* x = (const float*)d_in[0];
    float* out = (float*)d_out;
    int* ws = (int*)d_ws;
    int n_rows   = in_sizes[0] / (2 * N_T);       // 1024
    int n_chunks = n_rows * CPR;                  // 4096 (needs 16 KB of ws)

    chunk_sum_kernel<<<n_chunks, 256, 0, stream>>>(x, ws);
    if (out_size >= in_sizes[0]) {
        phase_kernel<1><<<n_chunks, 256, 0, stream>>>(x, out, ws);
    } else {
        phase_kernel<0><<<n_chunks, 256, 0, stream>>>(x, out, ws);
    }
}